// Round 1
// baseline (256.645 us; speedup 1.0000x reference)
//
#include <hip/hip_runtime.h>
#include <hip/hip_bf16.h>
#include <math.h>

#define N_NODES 20000
#define N_EDGES 320000
#define E_TOT   (N_EDGES + N_NODES)
#define N_FEAT  128
#define HID     64
#define HEADS   4
#define N_CLS   16
#define NEG_SLOPE 0.2f

__device__ __forceinline__ float wave_max(float v){
  #pragma unroll
  for (int off = 32; off; off >>= 1) v = fmaxf(v, __shfl_xor(v, off));
  return v;
}
__device__ __forceinline__ float wave_sum(float v){
  #pragma unroll
  for (int off = 32; off; off >>= 1) v += __shfl_xor(v, off);
  return v;
}

// ---- zero degree + cursor arrays (ws is poisoned 0xAA, must init every call) ----
__global__ void k_zero(int* __restrict__ deg, int* __restrict__ cur){
  int i = blockIdx.x * blockDim.x + threadIdx.x;
  if (i < N_NODES){ deg[i] = 0; cur[i] = 0; }
}

// ---- degree histogram over dst (includes self-loops) ----
__global__ void k_deg(const int* __restrict__ ei, int* __restrict__ deg){
  int e = blockIdx.x * blockDim.x + threadIdx.x;
  if (e >= E_TOT) return;
  int d = (e < N_EDGES) ? ei[N_EDGES + e] : (e - N_EDGES);
  atomicAdd(&deg[d], 1);
}

// ---- single-block exclusive scan of degrees -> row0[N_NODES+1] ----
__global__ void k_scan(const int* __restrict__ deg, int* __restrict__ row0){
  __shared__ int part[1024];
  int t = threadIdx.x;
  const int chunk = (N_NODES + 1023) / 1024;   // 20
  int base = t * chunk;
  int s = 0;
  for (int i = 0; i < chunk; ++i){ int idx = base + i; if (idx < N_NODES) s += deg[idx]; }
  part[t] = s; __syncthreads();
  for (int off = 1; off < 1024; off <<= 1){
    int v = (t >= off) ? part[t - off] : 0;
    __syncthreads();
    part[t] += v;
    __syncthreads();
  }
  int run = part[t] - s;  // exclusive prefix of this thread's chunk
  for (int i = 0; i < chunk; ++i){
    int idx = base + i;
    if (idx < N_NODES){ row0[idx] = run; run += deg[idx]; }
  }
  if (t == 1023) row0[N_NODES] = part[1023];
}

// ---- CSR placement (bucket order race-dependent; only perturbs fp sum order) ----
__global__ void k_place(const int* __restrict__ ei, const int* __restrict__ row0,
                        int* __restrict__ cur, int* __restrict__ adj){
  int e = blockIdx.x * blockDim.x + threadIdx.x;
  if (e >= E_TOT) return;
  int d = (e < N_EDGES) ? ei[N_EDGES + e] : (e - N_EDGES);
  int pos = atomicAdd(&cur[d], 1);
  adj[row0[d] + pos] = e;
}

// ---- GEMM1: h1[20000,256] = x[20000,128] @ W1[128,256] ----
// grid (313, 4), block 256. 64x64 tile, K in 2 chunks of 64, 4x4 micro-tile.
__global__ void k_gemm1(const float* __restrict__ x, const float* __restrict__ W,
                        float* __restrict__ h1){
  __shared__ float As[64][68];
  __shared__ float Bs[64][68];
  int t  = threadIdx.x;
  int tx = t & 15, ty = t >> 4;
  int m0 = blockIdx.x * 64;
  int j0 = blockIdx.y * 64;
  float acc[4][4] = {};
  for (int kk = 0; kk < 2; ++kk){
    #pragma unroll
    for (int ii = 0; ii < 4; ++ii){
      int f = t + ii * 256;          // 0..1023 float4 slots
      int r = f >> 4, c4 = f & 15;
      int grow = m0 + r;
      float4 av = make_float4(0.f, 0.f, 0.f, 0.f);
      if (grow < N_NODES) av = *(const float4*)&x[(size_t)grow * N_FEAT + kk * 64 + c4 * 4];
      *(float4*)&As[r][c4 * 4] = av;
      float4 bv = *(const float4*)&W[(size_t)(kk * 64 + r) * 256 + j0 + c4 * 4];
      *(float4*)&Bs[r][c4 * 4] = bv;
    }
    __syncthreads();
    #pragma unroll 8
    for (int k = 0; k < 64; ++k){
      float4 b = *(const float4*)&Bs[k][tx * 4];
      float a0 = As[ty * 4 + 0][k];
      float a1 = As[ty * 4 + 1][k];
      float a2 = As[ty * 4 + 2][k];
      float a3 = As[ty * 4 + 3][k];
      acc[0][0] += a0 * b.x; acc[0][1] += a0 * b.y; acc[0][2] += a0 * b.z; acc[0][3] += a0 * b.w;
      acc[1][0] += a1 * b.x; acc[1][1] += a1 * b.y; acc[1][2] += a1 * b.z; acc[1][3] += a1 * b.w;
      acc[2][0] += a2 * b.x; acc[2][1] += a2 * b.y; acc[2][2] += a2 * b.z; acc[2][3] += a2 * b.w;
      acc[3][0] += a3 * b.x; acc[3][1] += a3 * b.y; acc[3][2] += a3 * b.z; acc[3][3] += a3 * b.w;
    }
    __syncthreads();
  }
  #pragma unroll
  for (int i = 0; i < 4; ++i){
    int grow = m0 + ty * 4 + i;
    if (grow < N_NODES){
      float4 v = make_float4(acc[i][0], acc[i][1], acc[i][2], acc[i][3]);
      *(float4*)&h1[(size_t)grow * 256 + j0 + tx * 4] = v;
    }
  }
}

// ---- attention logit projections, layer 1: al = sum_c h1[n,h,c]*a[h,c] ----
__global__ void k_alproj1(const float* __restrict__ h1, const float* __restrict__ as1,
                          const float* __restrict__ ad1,
                          float* __restrict__ alS, float* __restrict__ alD){
  int n = blockIdx.x;
  int h = threadIdx.x >> 6, lane = threadIdx.x & 63;
  float v = h1[(size_t)n * 256 + h * 64 + lane];
  float s = wave_sum(v * as1[h * 64 + lane]);
  float d = wave_sum(v * ad1[h * 64 + lane]);
  if (lane == 0){ alS[n * 4 + h] = s; alD[n * 4 + h] = d; }
}

// ---- layer-1 softmax + aggregate + bias + ELU. block=node, wave=head ----
__global__ void k_attn1(const int* __restrict__ ei, const int* __restrict__ row0,
                        const int* __restrict__ adj, const float* __restrict__ h1,
                        const float* __restrict__ alS, const float* __restrict__ alD,
                        const float* __restrict__ b1,
                        float* __restrict__ wbuf, float* __restrict__ helu){
  int n = blockIdx.x;
  int h = threadIdx.x >> 6, lane = threadIdx.x & 63;
  int start = row0[n], end = row0[n + 1];
  float ald = alD[n * 4 + h];
  // phase 1a: max over incoming edges (lanes parallel over edges)
  float mloc = -INFINITY;
  for (int i = start + lane; i < end; i += 64){
    int e = adj[i];
    int s = (e < N_EDGES) ? ei[e] : (e - N_EDGES);
    float v = alS[s * 4 + h] + ald;
    v = (v > 0.f) ? v : NEG_SLOPE * v;
    mloc = fmaxf(mloc, v);
  }
  float m = wave_max(mloc);
  // phase 1b: exp + denom
  float ssum = 0.f;
  for (int i = start + lane; i < end; i += 64){
    int e = adj[i];
    int s = (e < N_EDGES) ? ei[e] : (e - N_EDGES);
    float v = alS[s * 4 + h] + ald;
    v = (v > 0.f) ? v : NEG_SLOPE * v;
    float w = __expf(v - m);
    wbuf[(size_t)i * 4 + h] = w;
    ssum += w;
  }
  float denom = wave_sum(ssum);
  float rinv = 1.f / (denom + 1e-16f);
  // phase 2: lanes = channels, sequential over edges
  float acc = 0.f;
  for (int i = start; i < end; ++i){
    int e = adj[i];
    int s = (e < N_EDGES) ? ei[e] : (e - N_EDGES);
    float w = wbuf[(size_t)i * 4 + h] * rinv;
    acc += w * h1[(size_t)s * 256 + h * 64 + lane];
  }
  float o = acc + b1[h * 64 + lane];
  o = (o > 0.f) ? o : (__expf(o) - 1.f);   // ELU
  helu[(size_t)n * 256 + h * 64 + lane] = o;
}

// ---- GEMM2: h2[20000,16] = helu[20000,256] @ W2[256,16] + b2 ----
// grid 1250, block 256: 16 nodes x 16 cols per block, full K staged in LDS.
__global__ void k_gemm2(const float* __restrict__ helu, const float* __restrict__ W2,
                        const float* __restrict__ b2, float* __restrict__ h2){
  __shared__ float As[16][260];
  __shared__ float Ws[256][16];
  int t = threadIdx.x;
  int n0 = blockIdx.x * 16;
  #pragma unroll
  for (int ii = 0; ii < 4; ++ii){
    int f = t + ii * 256;            // 0..1023 float4 slots
    { int r = f >> 6, c4 = f & 63;   // A: 16 rows x 64 float4
      float4 v = *(const float4*)&helu[(size_t)(n0 + r) * 256 + c4 * 4];
      *(float4*)&As[r][c4 * 4] = v; }
    { int k = f >> 2, q = f & 3;     // W2: 256 rows x 4 float4
      float4 v = *(const float4*)&W2[(size_t)k * 16 + q * 4];
      *(float4*)&Ws[k][q * 4] = v; }
  }
  __syncthreads();
  int col = t & 15, r = t >> 4;
  float acc = 0.f;
  #pragma unroll 4
  for (int k = 0; k < 256; k += 4){
    float4 a = *(const float4*)&As[r][k];
    acc += a.x * Ws[k][col] + a.y * Ws[k + 1][col] + a.z * Ws[k + 2][col] + a.w * Ws[k + 3][col];
  }
  h2[(size_t)(n0 + r) * 16 + col] = acc + b2[col];
}

// ---- layer-2 projections ----
__global__ void k_alproj2(const float* __restrict__ h2, const float* __restrict__ as2,
                          const float* __restrict__ ad2,
                          float* __restrict__ alS, float* __restrict__ alD){
  int n = blockIdx.x * blockDim.x + threadIdx.x;
  if (n >= N_NODES) return;
  float s = 0.f, d = 0.f;
  #pragma unroll
  for (int c = 0; c < 16; ++c){
    float v = h2[(size_t)n * 16 + c];
    s += v * as2[c]; d += v * ad2[c];
  }
  alS[n] = s; alD[n] = d;
}

// ---- layer-2 softmax + aggregate + bias -> d_out. wave=node ----
__global__ void k_attn2(const int* __restrict__ ei, const int* __restrict__ row0,
                        const int* __restrict__ adj, const float* __restrict__ h2,
                        const float* __restrict__ alS, const float* __restrict__ alD,
                        const float* __restrict__ b2,
                        float* __restrict__ wbuf, float* __restrict__ out){
  int n = blockIdx.x * 4 + (threadIdx.x >> 6);
  int lane = threadIdx.x & 63;
  int start = row0[n], end = row0[n + 1];
  float ald = alD[n];
  float mloc = -INFINITY;
  for (int i = start + lane; i < end; i += 64){
    int e = adj[i];
    int s = (e < N_EDGES) ? ei[e] : (e - N_EDGES);
    float v = alS[s] + ald;
    v = (v > 0.f) ? v : NEG_SLOPE * v;
    mloc = fmaxf(mloc, v);
  }
  float m = wave_max(mloc);
  float ssum = 0.f;
  for (int i = start + lane; i < end; i += 64){
    int e = adj[i];
    int s = (e < N_EDGES) ? ei[e] : (e - N_EDGES);
    float v = alS[s] + ald;
    v = (v > 0.f) ? v : NEG_SLOPE * v;
    float w = __expf(v - m);
    wbuf[i] = w;
    ssum += w;
  }
  float denom = wave_sum(ssum);
  float rinv = 1.f / (denom + 1e-16f);
  // phase 2: lane = (edge-group j)*16 + channel c
  int c = lane & 15, j = lane >> 4;
  float acc = 0.f;
  for (int i = start + j; i < end; i += 4){
    int e = adj[i];
    int s = (e < N_EDGES) ? ei[e] : (e - N_EDGES);
    acc += wbuf[i] * h2[(size_t)s * 16 + c];
  }
  acc += __shfl_xor(acc, 16);
  acc += __shfl_xor(acc, 32);
  if (lane < 16) out[(size_t)n * 16 + lane] = acc * rinv + b2[lane];
}

extern "C" void kernel_launch(void* const* d_in, const int* in_sizes, int n_in,
                              void* d_out, int out_size, void* d_ws, size_t ws_size,
                              hipStream_t stream){
  const float* x   = (const float*)d_in[0];
  const int*   ei  = (const int*)d_in[1];
  const float* W1  = (const float*)d_in[2];
  const float* as1 = (const float*)d_in[3];
  const float* ad1 = (const float*)d_in[4];
  const float* b1  = (const float*)d_in[5];
  const float* W2  = (const float*)d_in[6];
  const float* as2 = (const float*)d_in[7];
  const float* ad2 = (const float*)d_in[8];
  const float* b2  = (const float*)d_in[9];
  float* out = (float*)d_out;

  float* fws = (float*)d_ws;
  size_t off = 0;
  float* h1   = fws + off; off += (size_t)N_NODES * 256;
  float* helu = fws + off; off += (size_t)N_NODES * 256;
  float* wbuf = fws + off; off += (size_t)E_TOT * 4;   // layer1 [E,4]; layer2 reuses [E]
  float* h2   = fws + off; off += (size_t)N_NODES * 16;
  float* alS1 = fws + off; off += N_NODES * 4;
  float* alD1 = fws + off; off += N_NODES * 4;
  float* alS2 = fws + off; off += N_NODES;
  float* alD2 = fws + off; off += N_NODES;
  int* deg  = (int*)(fws + off);
  int* row0 = deg + N_NODES;
  int* cur  = row0 + N_NODES + 1;
  int* adj  = cur + N_NODES;

  k_zero<<<(N_NODES + 255) / 256, 256, 0, stream>>>(deg, cur);
  k_gemm1<<<dim3(313, 4), 256, 0, stream>>>(x, W1, h1);
  k_alproj1<<<N_NODES, 256, 0, stream>>>(h1, as1, ad1, alS1, alD1);
  k_deg<<<(E_TOT + 255) / 256, 256, 0, stream>>>(ei, deg);
  k_scan<<<1, 1024, 0, stream>>>(deg, row0);
  k_place<<<(E_TOT + 255) / 256, 256, 0, stream>>>(ei, row0, cur, adj);
  k_attn1<<<N_NODES, 256, 0, stream>>>(ei, row0, adj, h1, alS1, alD1, b1, wbuf, helu);
  k_gemm2<<<1250, 256, 0, stream>>>(helu, W2, b2, h2);
  k_alproj2<<<(N_NODES + 255) / 256, 256, 0, stream>>>(h2, as2, ad2, alS2, alD2);
  k_attn2<<<N_NODES / 4, 256, 0, stream>>>(ei, row0, adj, h2, alS2, alD2, b2, wbuf, out);
}

// Round 2
// 171.189 us; speedup vs baseline: 1.4992x; 1.4992x over previous
//
#include <hip/hip_runtime.h>
#include <hip/hip_bf16.h>
#include <math.h>

#define N_NODES 20000
#define N_EDGES 320000
#define E_TOT   (N_EDGES + N_NODES)
#define N_FEAT  128
#define HID     64
#define HEADS   4
#define N_CLS   16
#define NEG_SLOPE 0.2f
#define AL_CAP  512   // per-wave LDS alpha capacity (max in-degree ~45 for this data)

__device__ __forceinline__ float wave_max(float v){
  #pragma unroll
  for (int off = 32; off; off >>= 1) v = fmaxf(v, __shfl_xor(v, off));
  return v;
}
__device__ __forceinline__ float wave_sum(float v){
  #pragma unroll
  for (int off = 32; off; off >>= 1) v += __shfl_xor(v, off);
  return v;
}

// ---- zero degree + cursor arrays (ws poisoned 0xAA -> must init every call) ----
__global__ void k_zero(int* __restrict__ deg, int* __restrict__ cur){
  int i = blockIdx.x * blockDim.x + threadIdx.x;
  if (i < N_NODES){ deg[i] = 0; cur[i] = 0; }
}

// ---- degree histogram over dst (includes self-loops) ----
__global__ void k_deg(const int* __restrict__ ei, int* __restrict__ deg){
  int e = blockIdx.x * blockDim.x + threadIdx.x;
  if (e >= E_TOT) return;
  int d = (e < N_EDGES) ? ei[N_EDGES + e] : (e - N_EDGES);
  atomicAdd(&deg[d], 1);
}

// ---- single-block exclusive scan of degrees -> row0[N_NODES+1] ----
__global__ void k_scan(const int* __restrict__ deg, int* __restrict__ row0){
  __shared__ int part[1024];
  int t = threadIdx.x;
  const int chunk = (N_NODES + 1023) / 1024;   // 20
  int base = t * chunk;
  int s = 0;
  for (int i = 0; i < chunk; ++i){ int idx = base + i; if (idx < N_NODES) s += deg[idx]; }
  part[t] = s; __syncthreads();
  for (int off = 1; off < 1024; off <<= 1){
    int v = (t >= off) ? part[t - off] : 0;
    __syncthreads();
    part[t] += v;
    __syncthreads();
  }
  int run = part[t] - s;
  for (int i = 0; i < chunk; ++i){
    int idx = base + i;
    if (idx < N_NODES){ row0[idx] = run; run += deg[idx]; }
  }
  if (t == 1023) row0[N_NODES] = part[1023];
}

// ---- CSR placement: store SOURCE node id directly (kills one indirection) ----
__global__ void k_place(const int* __restrict__ ei, const int* __restrict__ row0,
                        int* __restrict__ cur, int* __restrict__ adjS){
  int e = blockIdx.x * blockDim.x + threadIdx.x;
  if (e >= E_TOT) return;
  int s, d;
  if (e < N_EDGES){ s = ei[e]; d = ei[N_EDGES + e]; }
  else            { s = d = e - N_EDGES; }
  int pos = atomicAdd(&cur[d], 1);
  adjS[row0[d] + pos] = s;
}

// ---- GEMM1: h1 = x @ W1  [20000,256], fused attention-logit projections ----
// grid (313, 4): blockIdx.y == head (cols by*64..by*64+63). 64x64 tile, 4x4 micro.
__global__ void k_gemm1(const float* __restrict__ x, const float* __restrict__ W,
                        const float* __restrict__ as1, const float* __restrict__ ad1,
                        float* __restrict__ h1,
                        float* __restrict__ alS, float* __restrict__ alD){
  __shared__ float As[64][68];
  __shared__ float Bs[64][68];
  int t  = threadIdx.x;
  int tx = t & 15, ty = t >> 4;
  int m0 = blockIdx.x * 64;
  int by = blockIdx.y;           // head
  int j0 = by * 64;
  float acc[4][4] = {};
  for (int kk = 0; kk < 2; ++kk){
    #pragma unroll
    for (int ii = 0; ii < 4; ++ii){
      int f = t + ii * 256;
      int r = f >> 4, c4 = f & 15;
      int grow = m0 + r;
      float4 av = make_float4(0.f, 0.f, 0.f, 0.f);
      if (grow < N_NODES) av = *(const float4*)&x[(size_t)grow * N_FEAT + kk * 64 + c4 * 4];
      *(float4*)&As[r][c4 * 4] = av;
      float4 bv = *(const float4*)&W[(size_t)(kk * 64 + r) * 256 + j0 + c4 * 4];
      *(float4*)&Bs[r][c4 * 4] = bv;
    }
    __syncthreads();
    #pragma unroll 8
    for (int k = 0; k < 64; ++k){
      float4 b = *(const float4*)&Bs[k][tx * 4];
      float a0 = As[ty * 4 + 0][k];
      float a1 = As[ty * 4 + 1][k];
      float a2 = As[ty * 4 + 2][k];
      float a3 = As[ty * 4 + 3][k];
      acc[0][0] += a0 * b.x; acc[0][1] += a0 * b.y; acc[0][2] += a0 * b.z; acc[0][3] += a0 * b.w;
      acc[1][0] += a1 * b.x; acc[1][1] += a1 * b.y; acc[1][2] += a1 * b.z; acc[1][3] += a1 * b.w;
      acc[2][0] += a2 * b.x; acc[2][1] += a2 * b.y; acc[2][2] += a2 * b.z; acc[2][3] += a2 * b.w;
      acc[3][0] += a3 * b.x; acc[3][1] += a3 * b.y; acc[3][2] += a3 * b.z; acc[3][3] += a3 * b.w;
    }
    __syncthreads();
  }
  float4 asv = *(const float4*)&as1[j0 + tx * 4];
  float4 adv = *(const float4*)&ad1[j0 + tx * 4];
  #pragma unroll
  for (int i = 0; i < 4; ++i){
    int grow = m0 + ty * 4 + i;
    float s_ = acc[i][0] * asv.x + acc[i][1] * asv.y + acc[i][2] * asv.z + acc[i][3] * asv.w;
    float d_ = acc[i][0] * adv.x + acc[i][1] * adv.y + acc[i][2] * adv.z + acc[i][3] * adv.w;
    #pragma unroll
    for (int off = 8; off; off >>= 1){ s_ += __shfl_xor(s_, off); d_ += __shfl_xor(d_, off); }
    if (grow < N_NODES){
      float4 v = make_float4(acc[i][0], acc[i][1], acc[i][2], acc[i][3]);
      *(float4*)&h1[(size_t)grow * 256 + j0 + tx * 4] = v;
      if (tx == 0){ alS[grow * 4 + by] = s_; alD[grow * 4 + by] = d_; }
    }
  }
}

// ---- layer-1 softmax + aggregate + bias + ELU.
// Block = 4 waves, ALL the SAME head (head = blockIdx&3 via XCD slot) on 4
// consecutive nodes -> each XCD's L2 only caches one head's 5.1MB h1 slice.
__global__ __launch_bounds__(256) void k_attn1(
                        const int* __restrict__ row0, const int* __restrict__ adjS,
                        const float* __restrict__ h1,
                        const float* __restrict__ alS, const float* __restrict__ alD,
                        const float* __restrict__ b1, float* __restrict__ helu){
  __shared__ float wsh[4][AL_CAP];
  int b    = blockIdx.x;
  int slot = b & 7;
  int h    = slot & 3;
  int g    = (slot >> 2) * 2500 + (b >> 3);   // node group [0,5000)
  int w    = threadIdx.x >> 6;
  int lane = threadIdx.x & 63;
  int n    = g * 4 + w;

  int start = __builtin_amdgcn_readfirstlane(row0[n]);
  int end   = __builtin_amdgcn_readfirstlane(row0[n + 1]);
  int deg   = end - start;
  float ald = alD[n * 4 + h];

  // phase 1a: leaky-relu logits -> LDS, wave max (lanes parallel over edges)
  float mloc = -INFINITY;
  for (int i = start + lane; i < end; i += 64){
    int s = adjS[i];
    float t = alS[s * 4 + h] + ald;
    t = (t > 0.f) ? t : NEG_SLOPE * t;
    if (i - start < AL_CAP) wsh[w][i - start] = t;
    mloc = fmaxf(mloc, t);
  }
  float m = wave_max(mloc);
  __builtin_amdgcn_wave_barrier();
  // phase 1b: exp in place, wave sum
  float ssum = 0.f;
  for (int i = start + lane; i < end; i += 64){
    int idx = i - start;
    float t;
    if (idx < AL_CAP) t = wsh[w][idx];
    else { int s = adjS[i]; t = alS[s * 4 + h] + ald; t = (t > 0.f) ? t : NEG_SLOPE * t; }
    float wv = __expf(t - m);
    if (idx < AL_CAP) wsh[w][idx] = wv;
    ssum += wv;
  }
  float rinv = 1.f / (wave_sum(ssum) + 1e-16f);
  __builtin_amdgcn_wave_barrier();

  // phase 2: lanes = 64 channels, 4-way ILP over edges
  const float* __restrict__ hb = h1 + (size_t)h * 64 + lane;
  float o;
  if (deg <= AL_CAP){
    float acc0 = 0.f, acc1 = 0.f, acc2 = 0.f, acc3 = 0.f;
    int i = start;
    for (; i + 4 <= end; i += 4){
      int s0 = __builtin_amdgcn_readfirstlane(adjS[i]);
      int s1 = __builtin_amdgcn_readfirstlane(adjS[i + 1]);
      int s2 = __builtin_amdgcn_readfirstlane(adjS[i + 2]);
      int s3 = __builtin_amdgcn_readfirstlane(adjS[i + 3]);
      int idx = i - start;
      float w0 = wsh[w][idx], w1 = wsh[w][idx + 1], w2 = wsh[w][idx + 2], w3 = wsh[w][idx + 3];
      acc0 += w0 * hb[(size_t)s0 * 256];
      acc1 += w1 * hb[(size_t)s1 * 256];
      acc2 += w2 * hb[(size_t)s2 * 256];
      acc3 += w3 * hb[(size_t)s3 * 256];
    }
    for (; i < end; ++i){
      int s0 = __builtin_amdgcn_readfirstlane(adjS[i]);
      acc0 += wsh[w][i - start] * hb[(size_t)s0 * 256];
    }
    o = ((acc0 + acc1) + (acc2 + acc3)) * rinv;
  } else {
    float acc = 0.f;   // cold path (never for this data, kept for correctness)
    for (int i = start; i < end; ++i){
      int s = __builtin_amdgcn_readfirstlane(adjS[i]);
      float t = alS[s * 4 + h] + ald;
      t = (t > 0.f) ? t : NEG_SLOPE * t;
      acc += __expf(t - m) * hb[(size_t)s * 256];
    }
    o = acc * rinv;
  }
  o += b1[h * 64 + lane];
  o = (o > 0.f) ? o : (__expf(o) - 1.f);   // ELU
  helu[(size_t)n * 256 + h * 64 + lane] = o;
}

// ---- GEMM2: h2 = helu @ W2 [20000,16] (pre-bias), fused layer-2 projections ----
__global__ void k_gemm2(const float* __restrict__ helu, const float* __restrict__ W2,
                        const float* __restrict__ as2, const float* __restrict__ ad2,
                        float* __restrict__ h2, float* __restrict__ alS, float* __restrict__ alD){
  __shared__ float As[16][260];
  __shared__ float Ws[256][16];
  int t = threadIdx.x;
  int n0 = blockIdx.x * 16;
  #pragma unroll
  for (int ii = 0; ii < 4; ++ii){
    int f = t + ii * 256;
    { int r = f >> 6, c4 = f & 63;
      float4 v = *(const float4*)&helu[(size_t)(n0 + r) * 256 + c4 * 4];
      *(float4*)&As[r][c4 * 4] = v; }
    { int k = f >> 2, q = f & 3;
      float4 v = *(const float4*)&W2[(size_t)k * 16 + q * 4];
      *(float4*)&Ws[k][q * 4] = v; }
  }
  __syncthreads();
  int col = t & 15, r = t >> 4;
  float acc = 0.f;
  #pragma unroll 4
  for (int k = 0; k < 256; k += 4){
    float4 a = *(const float4*)&As[r][k];
    acc += a.x * Ws[k][col] + a.y * Ws[k + 1][col] + a.z * Ws[k + 2][col] + a.w * Ws[k + 3][col];
  }
  h2[(size_t)(n0 + r) * 16 + col] = acc;          // pre-bias (ref applies bias after aggregate)
  float s_ = acc * as2[col];
  float d_ = acc * ad2[col];
  #pragma unroll
  for (int off = 8; off; off >>= 1){ s_ += __shfl_xor(s_, off); d_ += __shfl_xor(d_, off); }
  if (col == 0){ alS[n0 + r] = s_; alD[n0 + r] = d_; }
}

// ---- layer-2 softmax + aggregate + bias -> d_out. wave = node ----
__global__ __launch_bounds__(256) void k_attn2(
                        const int* __restrict__ row0, const int* __restrict__ adjS,
                        const float* __restrict__ h2,
                        const float* __restrict__ alS, const float* __restrict__ alD,
                        const float* __restrict__ b2, float* __restrict__ out){
  __shared__ float wsh[4][AL_CAP];
  int w    = threadIdx.x >> 6;
  int lane = threadIdx.x & 63;
  int n    = blockIdx.x * 4 + w;
  int start = __builtin_amdgcn_readfirstlane(row0[n]);
  int end   = __builtin_amdgcn_readfirstlane(row0[n + 1]);
  int deg   = end - start;
  float ald = alD[n];

  float mloc = -INFINITY;
  for (int i = start + lane; i < end; i += 64){
    int s = adjS[i];
    float t = alS[s] + ald;
    t = (t > 0.f) ? t : NEG_SLOPE * t;
    if (i - start < AL_CAP) wsh[w][i - start] = t;
    mloc = fmaxf(mloc, t);
  }
  float m = wave_max(mloc);
  __builtin_amdgcn_wave_barrier();
  float ssum = 0.f;
  for (int i = start + lane; i < end; i += 64){
    int idx = i - start;
    float t;
    if (idx < AL_CAP) t = wsh[w][idx];
    else { int s = adjS[i]; t = alS[s] + ald; t = (t > 0.f) ? t : NEG_SLOPE * t; }
    float wv = __expf(t - m);
    if (idx < AL_CAP) wsh[w][idx] = wv;
    ssum += wv;
  }
  float rinv = 1.f / (wave_sum(ssum) + 1e-16f);
  __builtin_amdgcn_wave_barrier();

  // phase 2: lane = j*16 + c ; 4 edge groups x 16 channels, 2-way ILP
  int c = lane & 15, j = lane >> 4;
  const float* __restrict__ hb = h2 + c;
  float acc;
  if (deg <= AL_CAP){
    float acc0 = 0.f, acc1 = 0.f;
    int i = start + j;
    for (; i + 4 < end; i += 8){
      int s0 = adjS[i], s1 = adjS[i + 4];
      acc0 += wsh[w][i - start] * hb[(size_t)s0 * 16];
      acc1 += wsh[w][i - start + 4] * hb[(size_t)s1 * 16];
    }
    for (; i < end; i += 4){
      int s0 = adjS[i];
      acc0 += wsh[w][i - start] * hb[(size_t)s0 * 16];
    }
    acc = acc0 + acc1;
  } else {
    acc = 0.f;
    for (int i = start + j; i < end; i += 4){
      int s = adjS[i];
      float t = alS[s] + ald;
      t = (t > 0.f) ? t : NEG_SLOPE * t;
      acc += __expf(t - m) * hb[(size_t)s * 16];
    }
  }
  acc += __shfl_xor(acc, 16);
  acc += __shfl_xor(acc, 32);
  if (lane < 16) out[(size_t)n * 16 + lane] = acc * rinv + b2[lane];
}

extern "C" void kernel_launch(void* const* d_in, const int* in_sizes, int n_in,
                              void* d_out, int out_size, void* d_ws, size_t ws_size,
                              hipStream_t stream){
  const float* x   = (const float*)d_in[0];
  const int*   ei  = (const int*)d_in[1];
  const float* W1  = (const float*)d_in[2];
  const float* as1 = (const float*)d_in[3];
  const float* ad1 = (const float*)d_in[4];
  const float* b1  = (const float*)d_in[5];
  const float* W2  = (const float*)d_in[6];
  const float* as2 = (const float*)d_in[7];
  const float* ad2 = (const float*)d_in[8];
  const float* b2  = (const float*)d_in[9];
  float* out = (float*)d_out;

  float* fws = (float*)d_ws;
  size_t off = 0;
  float* h1   = fws + off; off += (size_t)N_NODES * 256;
  float* helu = fws + off; off += (size_t)N_NODES * 256;
  float* h2   = fws + off; off += (size_t)N_NODES * 16;
  float* alS1 = fws + off; off += N_NODES * 4;
  float* alD1 = fws + off; off += N_NODES * 4;
  float* alS2 = fws + off; off += N_NODES;
  float* alD2 = fws + off; off += N_NODES;
  int* deg  = (int*)(fws + off);
  int* row0 = deg + N_NODES;
  int* cur  = row0 + N_NODES + 1;
  int* adjS = cur + N_NODES;

  k_zero<<<(N_NODES + 255) / 256, 256, 0, stream>>>(deg, cur);
  k_deg<<<(E_TOT + 255) / 256, 256, 0, stream>>>(ei, deg);
  k_scan<<<1, 1024, 0, stream>>>(deg, row0);
  k_place<<<(E_TOT + 255) / 256, 256, 0, stream>>>(ei, row0, cur, adjS);
  k_gemm1<<<dim3(313, 4), 256, 0, stream>>>(x, W1, as1, ad1, h1, alS1, alD1);
  k_attn1<<<N_NODES, 256, 0, stream>>>(row0, adjS, h1, alS1, alD1, b1, helu);
  k_gemm2<<<1250, 256, 0, stream>>>(helu, W2, as2, ad2, h2, alS2, alD2);
  k_attn2<<<N_NODES / 4, 256, 0, stream>>>(row0, adjS, h2, alS2, alD2, b2, out);
}